// Round 1
// baseline (137.396 us; speedup 1.0000x reference)
//
#include <hip/hip_runtime.h>

// out[b,o] = radius * (1/sqrt(K)) * sum_k cos(c*(w[o,k]-x[b,k])),  c = 2*pi/8
//          = radius * (1/sqrt(K)) * sum_k [cos(cx)cos(cw) + sin(cx)sin(cw)]
// B=2048, K=32768, O=10.  Memory-bound on reading x (256 MB).

#define K_DIM 32768
#define B_DIM 2048
#define O_DIM 10
#define BROWS 4                 // x rows per block
#define KCH 2                   // K chunks (grid = 512 row-groups x 2 = 1024 blocks)
#define KC_LEN (K_DIM / KCH)    // 16384
#define THREADS 256
#define QUADS_PER_THREAD (KC_LEN / (THREADS * 4))   // 16
#define INV_SQRT_K 0.005524271728019903f

// hardware v_sin/v_cos take REVOLUTIONS: sin(2*pi*r). c*x radians -> r = x/8.

__global__ void wtrig_kernel(const float* __restrict__ w,
                             float* __restrict__ cw,
                             float* __restrict__ sw) {
    int i = blockIdx.x * blockDim.x + threadIdx.x;   // exact: 1280*256 = 327680
    float r = w[i] * 0.125f;
    cw[i] = __builtin_amdgcn_cosf(r);
    sw[i] = __builtin_amdgcn_sinf(r);
}

__global__ __launch_bounds__(THREADS) void gsim_main(
        const float* __restrict__ x,
        const float* __restrict__ cw,
        const float* __restrict__ sw,
        float* __restrict__ part) {
    const int bid = blockIdx.x;
    const int rg = bid >> 1;          // row group
    const int kc = bid & 1;           // k chunk
    const int r0 = rg * BROWS;
    const int kbase = kc * KC_LEN;
    const int t = threadIdx.x;

    float acc[BROWS][O_DIM];
    #pragma unroll
    for (int r = 0; r < BROWS; ++r)
        #pragma unroll
        for (int o = 0; o < O_DIM; ++o) acc[r][o] = 0.f;

    const float4* xq0  = (const float4*)(x + (size_t)r0 * K_DIM + kbase);
    const float4* cwq0 = (const float4*)(cw + kbase);
    const float4* swq0 = (const float4*)(sw + kbase);
    const int fstride = K_DIM / 4;    // row stride in float4 units

    #pragma unroll 2
    for (int i = 0; i < QUADS_PER_THREAD; ++i) {
        const int q = t + i * THREADS;

        float cs[BROWS][4], sn[BROWS][4];
        #pragma unroll
        for (int r = 0; r < BROWS; ++r) {
            float4 xv = xq0[(size_t)r * fstride + q];
            const float* xp = (const float*)&xv;
            #pragma unroll
            for (int j = 0; j < 4; ++j) {
                float rr = xp[j] * 0.125f;      // revolutions
                cs[r][j] = __builtin_amdgcn_cosf(rr);
                sn[r][j] = __builtin_amdgcn_sinf(rr);
            }
        }

        #pragma unroll
        for (int o = 0; o < O_DIM; ++o) {
            float4 cv = cwq0[(size_t)o * fstride + q];
            float4 sv = swq0[(size_t)o * fstride + q];
            const float* cp = (const float*)&cv;
            const float* sp = (const float*)&sv;
            #pragma unroll
            for (int r = 0; r < BROWS; ++r)
                #pragma unroll
                for (int j = 0; j < 4; ++j)
                    acc[r][o] += cs[r][j] * cp[j] + sn[r][j] * sp[j];
        }
    }

    // 64-lane butterfly reduction per accumulator
    #pragma unroll
    for (int r = 0; r < BROWS; ++r)
        #pragma unroll
        for (int o = 0; o < O_DIM; ++o) {
            float v = acc[r][o];
            #pragma unroll
            for (int off = 32; off > 0; off >>= 1)
                v += __shfl_xor(v, off, 64);
            acc[r][o] = v;
        }

    __shared__ float red[THREADS / 64][BROWS * O_DIM];
    const int wave = t >> 6;
    const int lane = t & 63;
    if (lane == 0) {
        #pragma unroll
        for (int r = 0; r < BROWS; ++r)
            #pragma unroll
            for (int o = 0; o < O_DIM; ++o)
                red[wave][r * O_DIM + o] = acc[r][o];
    }
    __syncthreads();
    if (t < BROWS * O_DIM) {
        float v = red[0][t] + red[1][t] + red[2][t] + red[3][t];
        part[(size_t)kc * (B_DIM * O_DIM)
             + (size_t)(r0 + t / O_DIM) * O_DIM + (t % O_DIM)] = v;
    }
}

__global__ void finalize_kernel(const float* __restrict__ part,
                                const float* __restrict__ radius,
                                float* __restrict__ out) {
    int i = blockIdx.x * blockDim.x + threadIdx.x;
    if (i < B_DIM * O_DIM) {
        float v = part[i] + part[(size_t)B_DIM * O_DIM + i];
        out[i] = v * radius[0] * INV_SQRT_K;
    }
}

extern "C" void kernel_launch(void* const* d_in, const int* in_sizes, int n_in,
                              void* d_out, int out_size, void* d_ws, size_t ws_size,
                              hipStream_t stream) {
    const float* x      = (const float*)d_in[0];
    const float* w      = (const float*)d_in[1];
    const float* radius = (const float*)d_in[2];
    float* out = (float*)d_out;

    // workspace layout: cw[10][32768] f32 | sw[10][32768] f32 | part[2][2048][10] f32
    float* cw   = (float*)d_ws;
    float* sw   = cw + (size_t)O_DIM * K_DIM;
    float* part = sw + (size_t)O_DIM * K_DIM;

    hipLaunchKernelGGL(wtrig_kernel, dim3((O_DIM * K_DIM) / THREADS), dim3(THREADS),
                       0, stream, w, cw, sw);
    hipLaunchKernelGGL(gsim_main, dim3((B_DIM / BROWS) * KCH), dim3(THREADS),
                       0, stream, x, cw, sw, part);
    hipLaunchKernelGGL(finalize_kernel, dim3((B_DIM * O_DIM + THREADS - 1) / THREADS),
                       dim3(THREADS), 0, stream, part, radius, out);
}